// Round 1
// baseline (4498.295 us; speedup 1.0000x reference)
//
#include <hip/hip_runtime.h>
#include <math.h>

#define EPSV 1e-5f

// Problem constants
static constexpr int BB  = 4;
static constexpr int CC  = 512;
static constexpr int TT  = 16;
static constexpr int XX  = 2048;
static constexpr int HH  = 8;
static constexpr int HCH = 64;     // head channels
static constexpr int TXN = TT * XX;        // 32768
static constexpr int GROUP_N = 16 * TXN;   // 524288 elems per (b,g) group

// ---------------- K1a: per-group partial sums ----------------
// grid = 2048 blocks (128 groups * 16 sub-blocks), 256 threads.
__global__ __launch_bounds__(256) void k_gn_part(const float* __restrict__ x,
                                                 float* __restrict__ psum,
                                                 float* __restrict__ psq) {
    const int blk = blockIdx.x;
    const int tid = threadIdx.x;
    const float* p = x + (size_t)blk * 32768;
    float s = 0.f, q = 0.f;
#pragma unroll
    for (int i = 0; i < 32; ++i) {
        float4 v = *(const float4*)(p + (size_t)(i * 256 + tid) * 4);
        s += v.x + v.y + v.z + v.w;
        q += v.x * v.x + v.y * v.y + v.z * v.z + v.w * v.w;
    }
#pragma unroll
    for (int off = 32; off > 0; off >>= 1) {
        s += __shfl_down(s, off);
        q += __shfl_down(q, off);
    }
    __shared__ float ls[4], lq[4];
    const int wave = tid >> 6, lane = tid & 63;
    if (lane == 0) { ls[wave] = s; lq[wave] = q; }
    __syncthreads();
    if (tid == 0) {
        psum[blk] = ls[0] + ls[1] + ls[2] + ls[3];
        psq[blk]  = lq[0] + lq[1] + lq[2] + lq[3];
    }
}

// ---------------- K1b: finalize mean / rstd ----------------
// 1 block, 128 threads (one per (b,g))
__global__ void k_gn_final(const float* __restrict__ psum, const float* __restrict__ psq,
                           float* __restrict__ mu, float* __restrict__ rs) {
    const int t = threadIdx.x;  // 0..127
    float s = 0.f, q = 0.f;
#pragma unroll
    for (int i = 0; i < 16; ++i) { s += psum[t * 16 + i]; q += psq[t * 16 + i]; }
    const float m = s / (float)GROUP_N;
    float v = q / (float)GROUP_N - m * m;
    mu[t] = m;
    rs[t] = 1.0f / sqrtf(v + EPSV);
}

// ---------------- K2a: per-(b,c) scale/shift fold ----------------
// grid = 8 blocks * 256
__global__ __launch_bounds__(256) void k_fold_sc(const float* __restrict__ gn_w,
                                                 const float* __restrict__ gn_b,
                                                 const float* __restrict__ mu,
                                                 const float* __restrict__ rs,
                                                 float* __restrict__ sc,
                                                 float* __restrict__ beta) {
    const int u = blockIdx.x * 256 + threadIdx.x;  // 0..2047
    const int b = u >> 9, c = u & 511;
    const int g = c >> 4;
    const float r = rs[b * 32 + g], m = mu[b * 32 + g];
    const float s = r * gn_w[c];
    sc[u]   = s;
    beta[u] = gn_b[c] - m * s;
}

// ---------------- K2b: folded qkv bias (incl. k-scale) ----------------
// grid = 24 blocks * 256 (6144 outputs)
__global__ __launch_bounds__(256) void k_fold_bias(const float* __restrict__ qkv_w,
                                                   const float* __restrict__ qkv_b,
                                                   const float* __restrict__ beta,
                                                   float* __restrict__ qbias) {
    const int u = blockIdx.x * 256 + threadIdx.x;  // 0..6143
    const int b = u / 1536, o = u % 1536;
    float acc = qkv_b[o];
    const float* wr = qkv_w + (size_t)o * 512;
    const float* be = beta + b * 512;
#pragma unroll 4
    for (int c = 0; c < 512; c += 4) {
        float4 w4 = *(const float4*)(wr + c);
        float4 b4 = *(const float4*)(be + c);
        acc += w4.x * b4.x + w4.y * b4.y + w4.z * b4.z + w4.w * b4.w;
    }
    if (o >= 512 && o < 1024) acc *= 0.125f;  // fold 1/sqrt(64) into k
    qbias[u] = acc;
}

// ---------------- K3: fused GN-apply + QKV GEMM + attention ----------------
// grid = (H=8, X/4=512, B=4), 256 threads.
// Block computes qkv tile: 192 rows (q/k/v of head h) x 64 cols (16 t * 4 x),
// then attention over T=16 for the 4 x positions, writes `out` (into d_out).
__global__ __launch_bounds__(256) void k_qkv_attn(const float* __restrict__ x,
                                                  const float* __restrict__ qkv_w,
                                                  const float* __restrict__ sc,
                                                  const float* __restrict__ qbias,
                                                  const float* __restrict__ pos_emb,
                                                  float* __restrict__ out) {
    const int h  = blockIdx.x;
    const int x0 = blockIdx.y * 4;
    const int b  = blockIdx.z;
    const int tid = threadIdx.x;

    __shared__ float a_s[192][68];     // W' tile [m][cc]; later reused as qkv tile [m][col]
    __shared__ float b_s[64][68];      // x tile [cc][col]
    __shared__ float w_s[4][16][17];   // attention logits/weights [xx][t][u]

    const int ty = tid >> 3;  // 0..31 -> rows ty*6..+5
    const int tx = tid & 7;   // 0..7  -> cols tx*8..+7

    float acc[6][8];
#pragma unroll
    for (int j = 0; j < 6; ++j)
#pragma unroll
        for (int k = 0; k < 8; ++k) acc[j][k] = 0.f;

    for (int ko = 0; ko < 512; ko += 64) {
        __syncthreads();
        // A tile: 192 x 64, float4 over cc. W'[o,c] = qkv_w[o,c]*sc[b,c]*(k?0.125:1)
#pragma unroll
        for (int it = 0; it < 12; ++it) {
            int idx = it * 256 + tid;        // 0..3071
            int m = idx >> 4;                // 0..191
            int c4 = (idx & 15) * 4;         // 0..60
            int g = m >> 6, i = m & 63;
            int o = g * 512 + h * 64 + i;
            float4 w4 = *(const float4*)(qkv_w + (size_t)o * 512 + ko + c4);
            float4 s4 = *(const float4*)(sc + b * 512 + ko + c4);
            float ksc = (g == 1) ? 0.125f : 1.0f;
            float4 v;
            v.x = w4.x * s4.x * ksc; v.y = w4.y * s4.y * ksc;
            v.z = w4.z * s4.z * ksc; v.w = w4.w * s4.w * ksc;
            *(float4*)&a_s[m][c4] = v;
        }
        // B tile: 64 cc x 16 t, float4 over the 4 x's
#pragma unroll
        for (int it = 0; it < 4; ++it) {
            int idx = it * 256 + tid;        // 0..1023
            int cc = idx >> 4, t = idx & 15;
            float4 v = *(const float4*)(x + ((size_t)((b * 512 + ko + cc) * 16 + t)) * 2048 + x0);
            *(float4*)&b_s[cc][t * 4] = v;
        }
        __syncthreads();
#pragma unroll 4
        for (int cc = 0; cc < 64; ++cc) {
            float av[6];
#pragma unroll
            for (int j = 0; j < 6; ++j) av[j] = a_s[ty * 6 + j][cc];
            float4 b0 = *(const float4*)&b_s[cc][tx * 8];
            float4 b1 = *(const float4*)&b_s[cc][tx * 8 + 4];
            float bv[8] = {b0.x, b0.y, b0.z, b0.w, b1.x, b1.y, b1.z, b1.w};
#pragma unroll
            for (int j = 0; j < 6; ++j)
#pragma unroll
                for (int k = 0; k < 8; ++k)
                    acc[j][k] = fmaf(av[j], bv[k], acc[j][k]);
        }
    }
    // add folded bias
#pragma unroll
    for (int j = 0; j < 6; ++j) {
        int m = ty * 6 + j;
        int o = (m >> 6) * 512 + h * 64 + (m & 63);
        float qb = qbias[b * 1536 + o];
#pragma unroll
        for (int k = 0; k < 8; ++k) acc[j][k] += qb;
    }
    __syncthreads();
    // stash qkv tile into a_s: rows 0..63 = q(i), 64..127 = k(i), 128..191 = v(i)
#pragma unroll
    for (int j = 0; j < 6; ++j)
#pragma unroll
        for (int k = 0; k < 8; ++k)
            a_s[ty * 6 + j][tx * 8 + k] = acc[j][k];
    __syncthreads();

    // logits: L[xx][t][u] = sum_i q[i][t,xx] * k[i][u,xx]  (+ rel bias)
    {
        const int xx = tid >> 6;
        const int t  = (tid >> 2) & 15;
        const int uq = tid & 3;
        float l[4] = {0.f, 0.f, 0.f, 0.f};
        for (int i = 0; i < 64; ++i) {
            float qv = a_s[i][t * 4 + xx];
#pragma unroll
            for (int uu = 0; uu < 4; ++uu)
                l[uu] = fmaf(qv, a_s[64 + i][(uq * 4 + uu) * 4 + xx], l[uu]);
        }
#pragma unroll
        for (int uu = 0; uu < 4; ++uu) {
            int u = uq * 4 + uu;
            w_s[xx][t][u] = l[uu] + pos_emb[h * 32 + t - u + 15];
        }
    }
    __syncthreads();
    // softmax over u, per (xx,t)
    if (tid < 64) {
        const int xx = tid >> 4, t = tid & 15;
        float mx = -3.4e38f;
#pragma unroll
        for (int u = 0; u < 16; ++u) mx = fmaxf(mx, w_s[xx][t][u]);
        float ssum = 0.f;
#pragma unroll
        for (int u = 0; u < 16; ++u) {
            float e = __expf(w_s[xx][t][u] - mx);
            w_s[xx][t][u] = e;
            ssum += e;
        }
        float inv = 1.0f / ssum;
#pragma unroll
        for (int u = 0; u < 16; ++u) w_s[xx][t][u] *= inv;
    }
    __syncthreads();
    // PV: out[xx][i][t] = sum_u w[xx][t][u] * v[u][i,xx]; store float4 over xx
    {
        const int i  = tid & 63;
        const int t4 = tid >> 6;
        float4 varr[16];
#pragma unroll
        for (int u = 0; u < 16; ++u) varr[u] = *(const float4*)&a_s[128 + i][u * 4];
#pragma unroll
        for (int tt = 0; tt < 4; ++tt) {
            int t = t4 * 4 + tt;
            float4 o4 = {0.f, 0.f, 0.f, 0.f};
#pragma unroll
            for (int u = 0; u < 16; ++u) {
                o4.x = fmaf(w_s[0][t][u], varr[u].x, o4.x);
                o4.y = fmaf(w_s[1][t][u], varr[u].y, o4.y);
                o4.z = fmaf(w_s[2][t][u], varr[u].z, o4.z);
                o4.w = fmaf(w_s[3][t][u], varr[u].w, o4.w);
            }
            *(float4*)(out + ((size_t)((b * 512 + h * 64 + i) * 16 + t)) * 2048 + x0) = o4;
        }
    }
}

// ---------------- K4: in-place proj GEMM on d_out ----------------
// grid = (1024, 4), 256 threads; block handles (b, 32 consecutive (t,x) columns).
// Stages the 512x32 input tile in LDS first, then overwrites with y = P*in + pb.
__global__ __launch_bounds__(256) void k_proj(const float* __restrict__ pw,
                                              const float* __restrict__ pb,
                                              float* __restrict__ io) {
    const int n0 = blockIdx.x * 32;
    const int b  = blockIdx.y;
    const int tid = threadIdx.x;
    __shared__ float in_s[512][36];
    __shared__ float w_s[128][65];

    {
        const float* src = io + (size_t)b * 512 * 32768 + n0;
#pragma unroll
        for (int it = 0; it < 64; ++it) {
            int idx = it * 256 + tid;
            int r = idx >> 5, j = idx & 31;
            in_s[r][j] = src[(size_t)r * 32768 + j];
        }
    }
    __syncthreads();

    const int ty = tid >> 3;  // 0..31 -> rows ty*4..+3 (of 128-row chunk)
    const int tx = tid & 7;   // cols tx*4..+3

    for (int mo = 0; mo < 512; mo += 128) {
        float acc[4][4];
#pragma unroll
        for (int j = 0; j < 4; ++j)
#pragma unroll
            for (int k = 0; k < 4; ++k) acc[j][k] = 0.f;

        for (int ko = 0; ko < 512; ko += 64) {
            // load W chunk [128][64]
#pragma unroll
            for (int it = 0; it < 32; ++it) {
                int idx = it * 256 + tid;
                int m = idx >> 6, cc = idx & 63;
                w_s[m][cc] = pw[(size_t)(mo + m) * 512 + ko + cc];
            }
            __syncthreads();
#pragma unroll 4
            for (int cc = 0; cc < 64; ++cc) {
                float4 bv = *(const float4*)&in_s[ko + cc][tx * 4];
                float a0 = w_s[ty * 4 + 0][cc];
                float a1 = w_s[ty * 4 + 1][cc];
                float a2 = w_s[ty * 4 + 2][cc];
                float a3 = w_s[ty * 4 + 3][cc];
                acc[0][0] = fmaf(a0, bv.x, acc[0][0]); acc[0][1] = fmaf(a0, bv.y, acc[0][1]);
                acc[0][2] = fmaf(a0, bv.z, acc[0][2]); acc[0][3] = fmaf(a0, bv.w, acc[0][3]);
                acc[1][0] = fmaf(a1, bv.x, acc[1][0]); acc[1][1] = fmaf(a1, bv.y, acc[1][1]);
                acc[1][2] = fmaf(a1, bv.z, acc[1][2]); acc[1][3] = fmaf(a1, bv.w, acc[1][3]);
                acc[2][0] = fmaf(a2, bv.x, acc[2][0]); acc[2][1] = fmaf(a2, bv.y, acc[2][1]);
                acc[2][2] = fmaf(a2, bv.z, acc[2][2]); acc[2][3] = fmaf(a2, bv.w, acc[2][3]);
                acc[3][0] = fmaf(a3, bv.x, acc[3][0]); acc[3][1] = fmaf(a3, bv.y, acc[3][1]);
                acc[3][2] = fmaf(a3, bv.z, acc[3][2]); acc[3][3] = fmaf(a3, bv.w, acc[3][3]);
            }
            __syncthreads();
        }
#pragma unroll
        for (int j = 0; j < 4; ++j) {
            int m = mo + ty * 4 + j;
            float bias = pb[m];
            float4 o4 = {acc[j][0] + bias, acc[j][1] + bias, acc[j][2] + bias, acc[j][3] + bias};
            *(float4*)(io + (size_t)(b * 512 + m) * 32768 + n0 + tx * 4) = o4;
        }
    }
}

extern "C" void kernel_launch(void* const* d_in, const int* in_sizes, int n_in,
                              void* d_out, int out_size, void* d_ws, size_t ws_size,
                              hipStream_t stream) {
    (void)in_sizes; (void)n_in; (void)out_size; (void)ws_size;
    const float* x       = (const float*)d_in[0];
    const float* gn_w    = (const float*)d_in[1];
    const float* gn_b    = (const float*)d_in[2];
    const float* qkv_w   = (const float*)d_in[3];
    const float* qkv_b   = (const float*)d_in[4];
    const float* proj_w  = (const float*)d_in[5];
    const float* proj_b  = (const float*)d_in[6];
    const float* pos_emb = (const float*)d_in[7];
    float* out = (float*)d_out;

    float* ws    = (float*)d_ws;
    float* psum  = ws;            // 2048
    float* psq   = ws + 2048;     // 2048
    float* mu    = ws + 4096;     // 128
    float* rs    = ws + 4224;     // 128
    float* sc    = ws + 4352;     // 2048
    float* beta  = ws + 6400;     // 2048
    float* qbias = ws + 8448;     // 6144

    k_gn_part<<<dim3(2048), dim3(256), 0, stream>>>(x, psum, psq);
    k_gn_final<<<dim3(1), dim3(128), 0, stream>>>(psum, psq, mu, rs);
    k_fold_sc<<<dim3(8), dim3(256), 0, stream>>>(gn_w, gn_b, mu, rs, sc, beta);
    k_fold_bias<<<dim3(24), dim3(256), 0, stream>>>(qkv_w, qkv_b, beta, qbias);
    k_qkv_attn<<<dim3(8, 512, 4), dim3(256), 0, stream>>>(x, qkv_w, sc, qbias, pos_emb, out);
    k_proj<<<dim3(1024, 4), dim3(256), 0, stream>>>(proj_w, proj_b, out);
}

// Round 2
// 1126.140 us; speedup vs baseline: 3.9944x; 3.9944x over previous
//
#include <hip/hip_runtime.h>
#include <math.h>

#define EPSV 1e-5f

typedef _Float16 f16;
typedef _Float16 f16x8 __attribute__((ext_vector_type(8)));
typedef _Float16 f16x4 __attribute__((ext_vector_type(4)));
typedef float f32x4 __attribute__((ext_vector_type(4)));

static constexpr int GROUP_N = 16 * 16 * 2048;   // elems per (b,g) group

// ---------------- K1a: per-group partial sums ----------------
__global__ __launch_bounds__(256) void k_gn_part(const float* __restrict__ x,
                                                 float* __restrict__ psum,
                                                 float* __restrict__ psq) {
    const int blk = blockIdx.x;
    const int tid = threadIdx.x;
    const float* p = x + (size_t)blk * 32768;
    float s = 0.f, q = 0.f;
#pragma unroll
    for (int i = 0; i < 32; ++i) {
        float4 v = *(const float4*)(p + (size_t)(i * 256 + tid) * 4);
        s += v.x + v.y + v.z + v.w;
        q += v.x * v.x + v.y * v.y + v.z * v.z + v.w * v.w;
    }
#pragma unroll
    for (int off = 32; off > 0; off >>= 1) {
        s += __shfl_down(s, off);
        q += __shfl_down(q, off);
    }
    __shared__ float ls[4], lq[4];
    const int wave = tid >> 6, lane = tid & 63;
    if (lane == 0) { ls[wave] = s; lq[wave] = q; }
    __syncthreads();
    if (tid == 0) {
        psum[blk] = ls[0] + ls[1] + ls[2] + ls[3];
        psq[blk]  = lq[0] + lq[1] + lq[2] + lq[3];
    }
}

// ---------------- K1b: finalize mean / rstd ----------------
__global__ void k_gn_final(const float* __restrict__ psum, const float* __restrict__ psq,
                           float* __restrict__ mu, float* __restrict__ rs) {
    const int t = threadIdx.x;  // 0..127
    float s = 0.f, q = 0.f;
#pragma unroll
    for (int i = 0; i < 16; ++i) { s += psum[t * 16 + i]; q += psq[t * 16 + i]; }
    const float m = s / (float)GROUP_N;
    float v = q / (float)GROUP_N - m * m;
    mu[t] = m;
    rs[t] = 1.0f / sqrtf(v + EPSV);
}

// ---------------- K2a: per-(b,c) scale/shift fold ----------------
__global__ __launch_bounds__(256) void k_fold_sc(const float* __restrict__ gn_w,
                                                 const float* __restrict__ gn_b,
                                                 const float* __restrict__ mu,
                                                 const float* __restrict__ rs,
                                                 float* __restrict__ sc,
                                                 float* __restrict__ beta) {
    const int u = blockIdx.x * 256 + threadIdx.x;  // 0..2047
    const int b = u >> 9, c = u & 511;
    const int g = c >> 4;
    const float r = rs[b * 32 + g], m = mu[b * 32 + g];
    const float s = r * gn_w[c];
    sc[u]   = s;
    beta[u] = gn_b[c] - m * s;
}

// ---------------- K2b: folded qkv bias (fallback path only) ----------------
__global__ __launch_bounds__(256) void k_fold_bias(const float* __restrict__ qkv_w,
                                                   const float* __restrict__ qkv_b,
                                                   const float* __restrict__ beta,
                                                   float* __restrict__ qbias) {
    const int u = blockIdx.x * 256 + threadIdx.x;  // 0..6143
    const int b = u / 1536, o = u % 1536;
    float acc = qkv_b[o];
    const float* wr = qkv_w + (size_t)o * 512;
    const float* be = beta + b * 512;
#pragma unroll 4
    for (int c = 0; c < 512; c += 4) {
        float4 w4 = *(const float4*)(wr + c);
        float4 b4 = *(const float4*)(be + c);
        acc += w4.x * b4.x + w4.y * b4.y + w4.z * b4.z + w4.w * b4.w;
    }
    if (o >= 512 && o < 1024) acc *= 0.125f;
    qbias[u] = acc;
}

// ================= FAST PATH (fp16 MFMA) =================

// ---- prep: qkv_w -> fp16 (k-rows * 0.125), proj_w -> fp16 ----
__global__ __launch_bounds__(256) void k_prep_w(const float* __restrict__ qkv_w,
                                                const float* __restrict__ proj_w,
                                                f16* __restrict__ w16,
                                                f16* __restrict__ p16) {
    const int id = blockIdx.x * 256 + threadIdx.x;  // 0..262143
    if (id < 196608) {
        const int e0 = id * 4;
        const int o  = e0 >> 9;
        const float ksc = (o >= 512 && o < 1024) ? 0.125f : 1.0f;
        float4 v = *(const float4*)(qkv_w + e0);
        f16x4 h = { (f16)(v.x * ksc), (f16)(v.y * ksc), (f16)(v.z * ksc), (f16)(v.w * ksc) };
        *(f16x4*)(w16 + e0) = h;
    } else {
        const int e0 = (id - 196608) * 4;
        float4 v = *(const float4*)(proj_w + e0);
        f16x4 h = { (f16)v.x, (f16)v.y, (f16)v.z, (f16)v.w };
        *(f16x4*)(p16 + e0) = h;
    }
}

// ---- k_xt: x[b][c][t][x] fp32 -> xT[b][x][t][c] fp16, GN applied ----
// grid (32 xb, 8 cb, 64 = b*16+t), 256 threads
__global__ __launch_bounds__(256) void k_xt(const float* __restrict__ x,
                                            const float* __restrict__ sc,
                                            const float* __restrict__ beta,
                                            f16* __restrict__ xT) {
    const int x0 = blockIdx.x * 64;
    const int c0 = blockIdx.y * 64;
    const int b  = blockIdx.z >> 4, t = blockIdx.z & 15;
    const int tid = threadIdx.x;
    __shared__ float tile[64][68];
#pragma unroll
    for (int it = 0; it < 4; ++it) {
        int idx = it * 256 + tid;            // 0..1023
        int c = idx >> 4, xq = idx & 15;
        int cg = c0 + c;
        float s = sc[b * 512 + cg], be = beta[b * 512 + cg];
        float4 v = *(const float4*)(x + (((size_t)(b * 512 + cg) * 16 + t) * 2048) + x0 + xq * 4);
        tile[c][xq * 4 + 0] = v.x * s + be;
        tile[c][xq * 4 + 1] = v.y * s + be;
        tile[c][xq * 4 + 2] = v.z * s + be;
        tile[c][xq * 4 + 3] = v.w * s + be;
    }
    __syncthreads();
#pragma unroll
    for (int it = 0; it < 2; ++it) {
        int idx = it * 256 + tid;            // 0..511
        int xr = idx >> 3, ch = idx & 7;
        f16x8 h;
#pragma unroll
        for (int e = 0; e < 8; ++e) h[e] = (f16)tile[ch * 8 + e][xr];
        *(f16x8*)(xT + (((size_t)(b * 2048 + x0 + xr) * 16 + t) * 512) + c0 + ch * 8) = h;
    }
}

// ---- k3_mfma: fused QKV GEMM (fp16 MFMA) + attention ----
// grid (8 h, 256 xb, 4 b), 256 threads (4 waves, 2Mx2N)
__global__ __launch_bounds__(256) void k3_mfma(const f16* __restrict__ xT,
                                               const f16* __restrict__ w16,
                                               const float* __restrict__ qkv_b,
                                               const float* __restrict__ pos_emb,
                                               float* __restrict__ out) {
    const int h  = blockIdx.x;
    const int x0 = blockIdx.y * 8;
    const int b  = blockIdx.z;
    const int tid = threadIdx.x;
    const int lane = tid & 63, w = tid >> 6;
    const int wm = w >> 1, wn = w & 1;

    __shared__ __attribute__((aligned(16))) char smem[60928];
    __shared__ float bias_s[192];
    f16* a_s   = (f16*)smem;               // [192][64] swizzled
    f16* b_s   = (f16*)(smem + 24576);     // [128][64] swizzled
    f16* qkv_s = (f16*)smem;               // [192][136]
    float (*w_s)[16][17] = (float(*)[16][17])(smem + 52224);  // [8][16][17]

    if (tid < 192) {
        int g = tid >> 6;
        bias_s[tid] = qkv_b[g * 512 + h * 64 + (tid & 63)] * (g == 1 ? 0.125f : 1.0f);
    }

    f32x4 acc[6][4];
#pragma unroll
    for (int mi = 0; mi < 6; ++mi)
#pragma unroll
        for (int ni = 0; ni < 4; ++ni) acc[mi][ni] = (f32x4){0.f, 0.f, 0.f, 0.f};

    const size_t xT_base = ((size_t)b * 2048 + x0) * 16 * 512;

    for (int ko = 0; ko < 512; ko += 64) {
        __syncthreads();
        // stage A: W' 192x64
#pragma unroll
        for (int it = 0; it < 6; ++it) {
            int s = it * 256 + tid;          // 0..1535
            int m = s >> 3, ch = s & 7;
            int o = (m >> 6) * 512 + h * 64 + (m & 63);
            uint4 v = *(const uint4*)(w16 + (size_t)o * 512 + ko + ch * 8);
            *(uint4*)(a_s + m * 64 + ((ch ^ (m & 7)) * 8)) = v;
        }
        // stage B: xT 128(n) x 64(k)
#pragma unroll
        for (int it = 0; it < 4; ++it) {
            int s = it * 256 + tid;          // 0..1023
            int n = s >> 3, ch = s & 7;
            int t = n >> 3, xx = n & 7;
            uint4 v = *(const uint4*)(xT + xT_base + ((size_t)xx * 16 + t) * 512 + ko + ch * 8);
            *(uint4*)(b_s + n * 64 + ((ch ^ (n & 7)) * 8)) = v;
        }
        __syncthreads();
#pragma unroll
        for (int kk = 0; kk < 2; ++kk) {
            const int kb = kk * 4 + (lane >> 4);
            f16x8 af[6], bf[4];
#pragma unroll
            for (int mi = 0; mi < 6; ++mi) {
                int m = wm * 96 + mi * 16 + (lane & 15);
                af[mi] = *(const f16x8*)(a_s + m * 64 + ((kb ^ (m & 7)) * 8));
            }
#pragma unroll
            for (int ni = 0; ni < 4; ++ni) {
                int n = wn * 64 + ni * 16 + (lane & 15);
                bf[ni] = *(const f16x8*)(b_s + n * 64 + ((kb ^ (n & 7)) * 8));
            }
#pragma unroll
            for (int mi = 0; mi < 6; ++mi)
#pragma unroll
                for (int ni = 0; ni < 4; ++ni)
                    acc[mi][ni] = __builtin_amdgcn_mfma_f32_16x16x32_f16(af[mi], bf[ni], acc[mi][ni], 0, 0, 0);
        }
    }
    __syncthreads();
    // epilogue: acc + bias -> qkv_s fp16 [192][136]
#pragma unroll
    for (int mi = 0; mi < 6; ++mi)
#pragma unroll
        for (int ni = 0; ni < 4; ++ni) {
            int n  = wn * 64 + ni * 16 + (lane & 15);
            int mb = wm * 96 + mi * 16 + (lane >> 4) * 4;
#pragma unroll
            for (int r = 0; r < 4; ++r)
                qkv_s[(mb + r) * 136 + n] = (f16)(acc[mi][ni][r] + bias_s[mb + r]);
        }
    __syncthreads();
    // logits: each thread does (xx, t, 8 u's)
    {
        const int xx = tid >> 5, t = (tid >> 1) & 15, uh = tid & 1;
        float l[8] = {0.f, 0.f, 0.f, 0.f, 0.f, 0.f, 0.f, 0.f};
        for (int i = 0; i < 64; ++i) {
            float qv = (float)qkv_s[i * 136 + t * 8 + xx];
#pragma unroll
            for (int uu = 0; uu < 8; ++uu)
                l[uu] = fmaf(qv, (float)qkv_s[(64 + i) * 136 + (uh * 8 + uu) * 8 + xx], l[uu]);
        }
#pragma unroll
        for (int uu = 0; uu < 8; ++uu) {
            int u = uh * 8 + uu;
            w_s[xx][t][u] = l[uu] + pos_emb[h * 32 + t - u + 15];
        }
    }
    __syncthreads();
    if (tid < 128) {
        const int xx = tid >> 4, t = tid & 15;
        float mx = -3.4e38f;
#pragma unroll
        for (int u = 0; u < 16; ++u) mx = fmaxf(mx, w_s[xx][t][u]);
        float ssum = 0.f;
#pragma unroll
        for (int u = 0; u < 16; ++u) {
            float e = __expf(w_s[xx][t][u] - mx);
            w_s[xx][t][u] = e;
            ssum += e;
        }
        float inv = 1.0f / ssum;
#pragma unroll
        for (int u = 0; u < 16; ++u) w_s[xx][t][u] *= inv;
    }
    __syncthreads();
    // PV: out[b][h*64+i][t][x0..+8]
    {
        const int i = tid & 63, tq = tid >> 6;
        f16x8 v8[16];
#pragma unroll
        for (int u = 0; u < 16; ++u) v8[u] = *(const f16x8*)(qkv_s + (128 + i) * 136 + u * 8);
#pragma unroll
        for (int tt = 0; tt < 4; ++tt) {
            int t = tq * 4 + tt;
            float o8[8] = {0.f, 0.f, 0.f, 0.f, 0.f, 0.f, 0.f, 0.f};
#pragma unroll
            for (int u = 0; u < 16; ++u) {
#pragma unroll
                for (int xx = 0; xx < 8; ++xx)
                    o8[xx] = fmaf(w_s[xx][t][u], (float)v8[u][xx], o8[xx]);
            }
            float4 oa = {o8[0], o8[1], o8[2], o8[3]};
            float4 ob = {o8[4], o8[5], o8[6], o8[7]};
            size_t oaddr = (((size_t)b * 512 + h * 64 + i) * 16 + t) * 2048 + x0;
            *(float4*)(out + oaddr) = oa;
            *(float4*)(out + oaddr + 4) = ob;
        }
    }
}

// ---- k4_mfma: proj GEMM in-place on d_out, fp16 MFMA ----
// grid (32 xb, 16 t, 4 b), 256 threads (4 waves)
__global__ __launch_bounds__(256) void k4_mfma(const f16* __restrict__ p16,
                                               const float* __restrict__ pb,
                                               float* __restrict__ io) {
    const int x0 = blockIdx.x * 64;
    const int t  = blockIdx.y;
    const int b  = blockIdx.z;
    const int tid = threadIdx.x, lane = tid & 63, w = tid >> 6;

    __shared__ __attribute__((aligned(16))) char smem4[81920];
    f16* in_sT = (f16*)smem4;             // [64 xx][512 c] swizzled
    f16* bp_s  = (f16*)(smem4 + 65536);   // [128 o][64 c] swizzled

    const size_t base_in = (((size_t)b * 512) * 16 + t) * 2048 + x0;
#pragma unroll
    for (int it = 0; it < 32; ++it) {
        int s = it * 256 + tid;            // 0..8191
        int c = s >> 4, xq = s & 15;
        float4 v = *(const float4*)(io + base_in + (size_t)c * 16 * 2048 + xq * 4);
        int kc = c >> 3, j = c & 7;
        float vv[4] = {v.x, v.y, v.z, v.w};
#pragma unroll
        for (int e = 0; e < 4; ++e) {
            int xx = xq * 4 + e;
            in_sT[xx * 512 + ((kc ^ (xx & 7)) * 8) + j] = (f16)vv[e];
        }
    }

    for (int no = 0; no < 4; ++no) {
        const int o_base = no * 128;
        f32x4 acc[4][2];
#pragma unroll
        for (int mi = 0; mi < 4; ++mi)
#pragma unroll
            for (int nj = 0; nj < 2; ++nj) acc[mi][nj] = (f32x4){0.f, 0.f, 0.f, 0.f};

        for (int ko = 0; ko < 8; ++ko) {
            __syncthreads();
#pragma unroll
            for (int it = 0; it < 4; ++it) {
                int s = it * 256 + tid;    // 0..1023
                int orow = s >> 3, ch = s & 7;
                uint4 v = *(const uint4*)(p16 + (size_t)(o_base + orow) * 512 + ko * 64 + ch * 8);
                *(uint4*)(bp_s + orow * 64 + ((ch ^ (orow & 7)) * 8)) = v;
            }
            __syncthreads();
#pragma unroll
            for (int kk = 0; kk < 2; ++kk) {
                const int kb4 = kk * 4 + (lane >> 4);
                f16x8 af[4], bf[2];
#pragma unroll
                for (int mi = 0; mi < 4; ++mi) {
                    int xx = mi * 16 + (lane & 15);
                    int kc = ko * 8 + kb4;
                    af[mi] = *(const f16x8*)(in_sT + xx * 512 + ((kc ^ (xx & 7)) * 8));
                }
#pragma unroll
                for (int nj = 0; nj < 2; ++nj) {
                    int orow = w * 32 + nj * 16 + (lane & 15);
                    bf[nj] = *(const f16x8*)(bp_s + orow * 64 + ((kb4 ^ (orow & 7)) * 8));
                }
#pragma unroll
                for (int mi = 0; mi < 4; ++mi)
#pragma unroll
                    for (int nj = 0; nj < 2; ++nj)
                        acc[mi][nj] = __builtin_amdgcn_mfma_f32_16x16x32_f16(af[mi], bf[nj], acc[mi][nj], 0, 0, 0);
            }
        }
        // epilogue: y[o][t][x-window]
#pragma unroll
        for (int mi = 0; mi < 4; ++mi)
#pragma unroll
            for (int nj = 0; nj < 2; ++nj) {
                int o = o_base + w * 32 + nj * 16 + (lane & 15);
                int xxb = mi * 16 + (lane >> 4) * 4;
                float bias = pb[o];
                float4 ov = {acc[mi][nj][0] + bias, acc[mi][nj][1] + bias,
                             acc[mi][nj][2] + bias, acc[mi][nj][3] + bias};
                *(float4*)(io + (((size_t)b * 512 + o) * 16 + t) * 2048 + x0 + xxb) = ov;
            }
    }
}

// ================= FALLBACK PATH (R1 fp32, proven) =================

__global__ __launch_bounds__(256) void k_qkv_attn(const float* __restrict__ x,
                                                  const float* __restrict__ qkv_w,
                                                  const float* __restrict__ sc,
                                                  const float* __restrict__ qbias,
                                                  const float* __restrict__ pos_emb,
                                                  float* __restrict__ out) {
    const int h  = blockIdx.x;
    const int x0 = blockIdx.y * 4;
    const int b  = blockIdx.z;
    const int tid = threadIdx.x;

    __shared__ float a_s[192][68];
    __shared__ float b_s[64][68];
    __shared__ float w_s[4][16][17];

    const int ty = tid >> 3;
    const int tx = tid & 7;

    float acc[6][8];
#pragma unroll
    for (int j = 0; j < 6; ++j)
#pragma unroll
        for (int k = 0; k < 8; ++k) acc[j][k] = 0.f;

    for (int ko = 0; ko < 512; ko += 64) {
        __syncthreads();
#pragma unroll
        for (int it = 0; it < 12; ++it) {
            int idx = it * 256 + tid;
            int m = idx >> 4;
            int c4 = (idx & 15) * 4;
            int g = m >> 6, i = m & 63;
            int o = g * 512 + h * 64 + i;
            float4 w4 = *(const float4*)(qkv_w + (size_t)o * 512 + ko + c4);
            float4 s4 = *(const float4*)(sc + b * 512 + ko + c4);
            float ksc = (g == 1) ? 0.125f : 1.0f;
            float4 v;
            v.x = w4.x * s4.x * ksc; v.y = w4.y * s4.y * ksc;
            v.z = w4.z * s4.z * ksc; v.w = w4.w * s4.w * ksc;
            *(float4*)&a_s[m][c4] = v;
        }
#pragma unroll
        for (int it = 0; it < 4; ++it) {
            int idx = it * 256 + tid;
            int cc = idx >> 4, t = idx & 15;
            float4 v = *(const float4*)(x + ((size_t)((b * 512 + ko + cc) * 16 + t)) * 2048 + x0);
            *(float4*)&b_s[cc][t * 4] = v;
        }
        __syncthreads();
#pragma unroll 4
        for (int cc = 0; cc < 64; ++cc) {
            float av[6];
#pragma unroll
            for (int j = 0; j < 6; ++j) av[j] = a_s[ty * 6 + j][cc];
            float4 b0 = *(const float4*)&b_s[cc][tx * 8];
            float4 b1 = *(const float4*)&b_s[cc][tx * 8 + 4];
            float bv[8] = {b0.x, b0.y, b0.z, b0.w, b1.x, b1.y, b1.z, b1.w};
#pragma unroll
            for (int j = 0; j < 6; ++j)
#pragma unroll
                for (int k = 0; k < 8; ++k)
                    acc[j][k] = fmaf(av[j], bv[k], acc[j][k]);
        }
    }
#pragma unroll
    for (int j = 0; j < 6; ++j) {
        int m = ty * 6 + j;
        int o = (m >> 6) * 512 + h * 64 + (m & 63);
        float qb = qbias[b * 1536 + o];
#pragma unroll
        for (int k = 0; k < 8; ++k) acc[j][k] += qb;
    }
    __syncthreads();
#pragma unroll
    for (int j = 0; j < 6; ++j)
#pragma unroll
        for (int k = 0; k < 8; ++k)
            a_s[ty * 6 + j][tx * 8 + k] = acc[j][k];
    __syncthreads();

    {
        const int xx = tid >> 6;
        const int t  = (tid >> 2) & 15;
        const int uq = tid & 3;
        float l[4] = {0.f, 0.f, 0.f, 0.f};
        for (int i = 0; i < 64; ++i) {
            float qv = a_s[i][t * 4 + xx];
#pragma unroll
            for (int uu = 0; uu < 4; ++uu)
                l[uu] = fmaf(qv, a_s[64 + i][(uq * 4 + uu) * 4 + xx], l[uu]);
        }
#pragma unroll
        for (int uu = 0; uu < 4; ++uu) {
            int u = uq * 4 + uu;
            w_s[xx][t][u] = l[uu] + pos_emb[h * 32 + t - u + 15];
        }
    }
    __syncthreads();
    if (tid < 64) {
        const int xx = tid >> 4, t = tid & 15;
        float mx = -3.4e38f;
#pragma unroll
        for (int u = 0; u < 16; ++u) mx = fmaxf(mx, w_s[xx][t][u]);
        float ssum = 0.f;
#pragma unroll
        for (int u = 0; u < 16; ++u) {
            float e = __expf(w_s[xx][t][u] - mx);
            w_s[xx][t][u] = e;
            ssum += e;
        }
        float inv = 1.0f / ssum;
#pragma unroll
        for (int u = 0; u < 16; ++u) w_s[xx][t][u] *= inv;
    }
    __syncthreads();
    {
        const int i  = tid & 63;
        const int t4 = tid >> 6;
        float4 varr[16];
#pragma unroll
        for (int u = 0; u < 16; ++u) varr[u] = *(const float4*)&a_s[128 + i][u * 4];
#pragma unroll
        for (int tt = 0; tt < 4; ++tt) {
            int t = t4 * 4 + tt;
            float4 o4 = {0.f, 0.f, 0.f, 0.f};
#pragma unroll
            for (int u = 0; u < 16; ++u) {
                o4.x = fmaf(w_s[0][t][u], varr[u].x, o4.x);
                o4.y = fmaf(w_s[1][t][u], varr[u].y, o4.y);
                o4.z = fmaf(w_s[2][t][u], varr[u].z, o4.z);
                o4.w = fmaf(w_s[3][t][u], varr[u].w, o4.w);
            }
            *(float4*)(out + ((size_t)((b * 512 + h * 64 + i) * 16 + t)) * 2048 + x0) = o4;
        }
    }
}

__global__ __launch_bounds__(256) void k_proj(const float* __restrict__ pw,
                                              const float* __restrict__ pb,
                                              float* __restrict__ io) {
    const int n0 = blockIdx.x * 32;
    const int b  = blockIdx.y;
    const int tid = threadIdx.x;
    __shared__ float in_s[512][36];
    __shared__ float w_s[128][65];

    {
        const float* src = io + (size_t)b * 512 * 32768 + n0;
#pragma unroll
        for (int it = 0; it < 64; ++it) {
            int idx = it * 256 + tid;
            int r = idx >> 5, j = idx & 31;
            in_s[r][j] = src[(size_t)r * 32768 + j];
        }
    }
    __syncthreads();

    const int ty = tid >> 3;
    const int tx = tid & 7;

    for (int mo = 0; mo < 512; mo += 128) {
        float acc[4][4];
#pragma unroll
        for (int j = 0; j < 4; ++j)
#pragma unroll
            for (int k = 0; k < 4; ++k) acc[j][k] = 0.f;

        for (int ko = 0; ko < 512; ko += 64) {
#pragma unroll
            for (int it = 0; it < 32; ++it) {
                int idx = it * 256 + tid;
                int m = idx >> 6, cc = idx & 63;
                w_s[m][cc] = pw[(size_t)(mo + m) * 512 + ko + cc];
            }
            __syncthreads();
#pragma unroll 4
            for (int cc = 0; cc < 64; ++cc) {
                float4 bv = *(const float4*)&in_s[ko + cc][tx * 4];
                float a0 = w_s[ty * 4 + 0][cc];
                float a1 = w_s[ty * 4 + 1][cc];
                float a2 = w_s[ty * 4 + 2][cc];
                float a3 = w_s[ty * 4 + 3][cc];
                acc[0][0] = fmaf(a0, bv.x, acc[0][0]); acc[0][1] = fmaf(a0, bv.y, acc[0][1]);
                acc[0][2] = fmaf(a0, bv.z, acc[0][2]); acc[0][3] = fmaf(a0, bv.w, acc[0][3]);
                acc[1][0] = fmaf(a1, bv.x, acc[1][0]); acc[1][1] = fmaf(a1, bv.y, acc[1][1]);
                acc[1][2] = fmaf(a1, bv.z, acc[1][2]); acc[1][3] = fmaf(a1, bv.w, acc[1][3]);
                acc[2][0] = fmaf(a2, bv.x, acc[2][0]); acc[2][1] = fmaf(a2, bv.y, acc[2][1]);
                acc[2][2] = fmaf(a2, bv.z, acc[2][2]); acc[2][3] = fmaf(a2, bv.w, acc[2][3]);
                acc[3][0] = fmaf(a3, bv.x, acc[3][0]); acc[3][1] = fmaf(a3, bv.y, acc[3][1]);
                acc[3][2] = fmaf(a3, bv.z, acc[3][2]); acc[3][3] = fmaf(a3, bv.w, acc[3][3]);
            }
            __syncthreads();
        }
#pragma unroll
        for (int j = 0; j < 4; ++j) {
            int m = mo + ty * 4 + j;
            float bias = pb[m];
            float4 o4 = {acc[j][0] + bias, acc[j][1] + bias, acc[j][2] + bias, acc[j][3] + bias};
            *(float4*)(io + (size_t)(b * 512 + m) * 32768 + n0 + tx * 4) = o4;
        }
    }
}

extern "C" void kernel_launch(void* const* d_in, const int* in_sizes, int n_in,
                              void* d_out, int out_size, void* d_ws, size_t ws_size,
                              hipStream_t stream) {
    (void)in_sizes; (void)n_in; (void)out_size;
    const float* x       = (const float*)d_in[0];
    const float* gn_w    = (const float*)d_in[1];
    const float* gn_b    = (const float*)d_in[2];
    const float* qkv_w   = (const float*)d_in[3];
    const float* qkv_b   = (const float*)d_in[4];
    const float* proj_w  = (const float*)d_in[5];
    const float* proj_b  = (const float*)d_in[6];
    const float* pos_emb = (const float*)d_in[7];
    float* out = (float*)d_out;

    float* ws    = (float*)d_ws;
    float* psum  = ws;            // 2048
    float* psq   = ws + 2048;     // 2048
    float* mu    = ws + 4096;     // 128
    float* rs    = ws + 4224;     // 128
    float* sc    = ws + 4352;     // 2048
    float* beta  = ws + 6400;     // 2048
    float* qbias = ws + 8448;     // 6144

    // fast-path scratch layout (bytes)
    const size_t W16_OFF = 65536;
    const size_t P16_OFF = W16_OFF + (size_t)1536 * 512 * 2;
    const size_t XT_OFF  = P16_OFF + (size_t)512 * 512 * 2;
    const size_t NEEDED  = XT_OFF + (size_t)4 * 2048 * 16 * 512 * 2;

    k_gn_part<<<dim3(2048), dim3(256), 0, stream>>>(x, psum, psq);
    k_gn_final<<<dim3(1), dim3(128), 0, stream>>>(psum, psq, mu, rs);
    k_fold_sc<<<dim3(8), dim3(256), 0, stream>>>(gn_w, gn_b, mu, rs, sc, beta);

    if (ws_size >= NEEDED) {
        f16* w16 = (f16*)((char*)d_ws + W16_OFF);
        f16* p16 = (f16*)((char*)d_ws + P16_OFF);
        f16* xT  = (f16*)((char*)d_ws + XT_OFF);
        k_prep_w<<<dim3(1024), dim3(256), 0, stream>>>(qkv_w, proj_w, w16, p16);
        k_xt<<<dim3(32, 8, 64), dim3(256), 0, stream>>>(x, sc, beta, xT);
        k3_mfma<<<dim3(8, 256, 4), dim3(256), 0, stream>>>(xT, w16, qkv_b, pos_emb, out);
        k4_mfma<<<dim3(32, 16, 4), dim3(256), 0, stream>>>(p16, proj_b, out);
    } else {
        k_fold_bias<<<dim3(24), dim3(256), 0, stream>>>(qkv_w, qkv_b, beta, qbias);
        k_qkv_attn<<<dim3(8, 512, 4), dim3(256), 0, stream>>>(x, qkv_w, sc, qbias, pos_emb, out);
        k_proj<<<dim3(1024, 4), dim3(256), 0, stream>>>(proj_w, proj_b, out);
    }
}

// Round 3
// 689.359 us; speedup vs baseline: 6.5253x; 1.6336x over previous
//
#include <hip/hip_runtime.h>
#include <math.h>

#define EPSV 1e-5f

typedef _Float16 f16;
typedef _Float16 f16x8 __attribute__((ext_vector_type(8)));
typedef _Float16 f16x4 __attribute__((ext_vector_type(4)));
typedef float f32x4 __attribute__((ext_vector_type(4)));

static constexpr int GROUP_N = 16 * 16 * 2048;   // elems per (b,g) group

// ---------------- K1a: per-group partial sums ----------------
__global__ __launch_bounds__(256) void k_gn_part(const float* __restrict__ x,
                                                 float* __restrict__ psum,
                                                 float* __restrict__ psq) {
    const int blk = blockIdx.x;
    const int tid = threadIdx.x;
    const float* p = x + (size_t)blk * 32768;
    float s = 0.f, q = 0.f;
#pragma unroll
    for (int i = 0; i < 32; ++i) {
        float4 v = *(const float4*)(p + (size_t)(i * 256 + tid) * 4);
        s += v.x + v.y + v.z + v.w;
        q += v.x * v.x + v.y * v.y + v.z * v.z + v.w * v.w;
    }
#pragma unroll
    for (int off = 32; off > 0; off >>= 1) {
        s += __shfl_down(s, off);
        q += __shfl_down(q, off);
    }
    __shared__ float ls[4], lq[4];
    const int wave = tid >> 6, lane = tid & 63;
    if (lane == 0) { ls[wave] = s; lq[wave] = q; }
    __syncthreads();
    if (tid == 0) {
        psum[blk] = ls[0] + ls[1] + ls[2] + ls[3];
        psq[blk]  = lq[0] + lq[1] + lq[2] + lq[3];
    }
}

// ---------------- K1b: finalize mean / rstd ----------------
__global__ void k_gn_final(const float* __restrict__ psum, const float* __restrict__ psq,
                           float* __restrict__ mu, float* __restrict__ rs) {
    const int t = threadIdx.x;  // 0..127
    float s = 0.f, q = 0.f;
#pragma unroll
    for (int i = 0; i < 16; ++i) { s += psum[t * 16 + i]; q += psq[t * 16 + i]; }
    const float m = s / (float)GROUP_N;
    float v = q / (float)GROUP_N - m * m;
    mu[t] = m;
    rs[t] = 1.0f / sqrtf(v + EPSV);
}

// ---------------- K2a: per-(b,c) scale/shift fold ----------------
__global__ __launch_bounds__(256) void k_fold_sc(const float* __restrict__ gn_w,
                                                 const float* __restrict__ gn_b,
                                                 const float* __restrict__ mu,
                                                 const float* __restrict__ rs,
                                                 float* __restrict__ sc,
                                                 float* __restrict__ beta) {
    const int u = blockIdx.x * 256 + threadIdx.x;  // 0..2047
    const int b = u >> 9, c = u & 511;
    const int g = c >> 4;
    const float r = rs[b * 32 + g], m = mu[b * 32 + g];
    const float s = r * gn_w[c];
    sc[u]   = s;
    beta[u] = gn_b[c] - m * s;
}

// ---------------- K2b: folded qkv bias (fallback path only) ----------------
__global__ __launch_bounds__(256) void k_fold_bias(const float* __restrict__ qkv_w,
                                                   const float* __restrict__ qkv_b,
                                                   const float* __restrict__ beta,
                                                   float* __restrict__ qbias) {
    const int u = blockIdx.x * 256 + threadIdx.x;  // 0..6143
    const int b = u / 1536, o = u % 1536;
    float acc = qkv_b[o];
    const float* wr = qkv_w + (size_t)o * 512;
    const float* be = beta + b * 512;
#pragma unroll 4
    for (int c = 0; c < 512; c += 4) {
        float4 w4 = *(const float4*)(wr + c);
        float4 b4 = *(const float4*)(be + c);
        acc += w4.x * b4.x + w4.y * b4.y + w4.z * b4.z + w4.w * b4.w;
    }
    if (o >= 512 && o < 1024) acc *= 0.125f;
    qbias[u] = acc;
}

// ================= FAST PATH (fp16 MFMA) =================

__global__ __launch_bounds__(256) void k_prep_w(const float* __restrict__ qkv_w,
                                                const float* __restrict__ proj_w,
                                                f16* __restrict__ w16,
                                                f16* __restrict__ p16) {
    const int id = blockIdx.x * 256 + threadIdx.x;  // 0..262143
    if (id < 196608) {
        const int e0 = id * 4;
        const int o  = e0 >> 9;
        const float ksc = (o >= 512 && o < 1024) ? 0.125f : 1.0f;
        float4 v = *(const float4*)(qkv_w + e0);
        f16x4 h = { (f16)(v.x * ksc), (f16)(v.y * ksc), (f16)(v.z * ksc), (f16)(v.w * ksc) };
        *(f16x4*)(w16 + e0) = h;
    } else {
        const int e0 = (id - 196608) * 4;
        float4 v = *(const float4*)(proj_w + e0);
        f16x4 h = { (f16)v.x, (f16)v.y, (f16)v.z, (f16)v.w };
        *(f16x4*)(p16 + e0) = h;
    }
}

// ---- k_xt: x[b][c][t][x] fp32 -> xT[b][x][t][c] fp16, GN applied ----
__global__ __launch_bounds__(256) void k_xt(const float* __restrict__ x,
                                            const float* __restrict__ sc,
                                            const float* __restrict__ beta,
                                            f16* __restrict__ xT) {
    const int x0 = blockIdx.x * 64;
    const int c0 = blockIdx.y * 64;
    const int b  = blockIdx.z >> 4, t = blockIdx.z & 15;
    const int tid = threadIdx.x;
    __shared__ float tile[64][68];
#pragma unroll
    for (int it = 0; it < 4; ++it) {
        int idx = it * 256 + tid;            // 0..1023
        int c = idx >> 4, xq = idx & 15;
        int cg = c0 + c;
        float s = sc[b * 512 + cg], be = beta[b * 512 + cg];
        float4 v = *(const float4*)(x + (((size_t)(b * 512 + cg) * 16 + t) * 2048) + x0 + xq * 4);
        tile[c][xq * 4 + 0] = v.x * s + be;
        tile[c][xq * 4 + 1] = v.y * s + be;
        tile[c][xq * 4 + 2] = v.z * s + be;
        tile[c][xq * 4 + 3] = v.w * s + be;
    }
    __syncthreads();
#pragma unroll
    for (int it = 0; it < 2; ++it) {
        int idx = it * 256 + tid;            // 0..511
        int xr = idx >> 3, ch = idx & 7;
        f16x8 h;
#pragma unroll
        for (int e = 0; e < 8; ++e) h[e] = (f16)tile[ch * 8 + e][xr];
        *(f16x8*)(xT + (((size_t)(b * 2048 + x0 + xr) * 16 + t) * 512) + c0 + ch * 8) = h;
    }
}

// ---- k3_mfma: fused QKV GEMM + MFMA attention, all matrix-pipe ----
// grid (8 h, 256 xb, 4 b), 256 threads (4 waves, 2Mx2N for GEMM; 2 xx/wave for attn)
// LDS: phase1 a_s[192][64]swz + b_s[128][64]swz; phase2 qkvT[128 n][256 m] f16,
// 16B-chunk XOR swizzled (chunk' = region*8 + (chunk^ (n&7))). O overwrites the
// dead Q/K chunks of each wave's own rows (wave-private, no barrier).
__global__ __launch_bounds__(256) void k3_mfma(const f16* __restrict__ xT,
                                               const f16* __restrict__ w16,
                                               const float* __restrict__ qkv_b,
                                               const float* __restrict__ pos_emb,
                                               float* __restrict__ out) {
    const int h  = blockIdx.x;
    const int x0 = blockIdx.y * 8;
    const int b  = blockIdx.z;
    const int tid = threadIdx.x;
    const int lane = tid & 63, w = tid >> 6;
    const int wm = w >> 1, wn = w & 1;
    const int t_l = lane & 15, g = lane >> 4;

    __shared__ __attribute__((aligned(16))) char smem[66304];
    f16* a_s = (f16*)smem;                    // [192][64] swz (phase 1)
    f16* b_s = (f16*)(smem + 24576);          // [128][64] swz (phase 1)
    float* bias_s = (float*)(smem + 65536);   // 192 floats

    if (tid < 192) {
        int gr = tid >> 6;
        bias_s[tid] = qkv_b[gr * 512 + h * 64 + (tid & 63)] * (gr == 1 ? 0.125f : 1.0f);
    }

    f32x4 acc[6][4];
#pragma unroll
    for (int mi = 0; mi < 6; ++mi)
#pragma unroll
        for (int ni = 0; ni < 4; ++ni) acc[mi][ni] = (f32x4){0.f, 0.f, 0.f, 0.f};

    const size_t xT_base = ((size_t)b * 2048 + x0) * 16 * 512;

    for (int ko = 0; ko < 512; ko += 64) {
        __syncthreads();
        // stage A: W' 192x64
#pragma unroll
        for (int it = 0; it < 6; ++it) {
            int s = it * 256 + tid;
            int m = s >> 3, ch = s & 7;
            int o = (m >> 6) * 512 + h * 64 + (m & 63);
            uint4 v = *(const uint4*)(w16 + (size_t)o * 512 + ko + ch * 8);
            *(uint4*)(a_s + m * 64 + ((ch ^ (m & 7)) * 8)) = v;
        }
        // stage B: xT rows n = xx*16+t map 1:1 to xT's (x,t) order
#pragma unroll
        for (int it = 0; it < 4; ++it) {
            int s = it * 256 + tid;
            int n = s >> 3, ch = s & 7;
            uint4 v = *(const uint4*)(xT + xT_base + (size_t)n * 512 + ko + ch * 8);
            *(uint4*)(b_s + n * 64 + ((ch ^ (n & 7)) * 8)) = v;
        }
        __syncthreads();
#pragma unroll
        for (int kk = 0; kk < 2; ++kk) {
            const int kb = kk * 4 + g;
            f16x8 af[6], bf[4];
#pragma unroll
            for (int mi = 0; mi < 6; ++mi) {
                int m = wm * 96 + mi * 16 + t_l;
                af[mi] = *(const f16x8*)(a_s + m * 64 + ((kb ^ (m & 7)) * 8));
            }
#pragma unroll
            for (int ni = 0; ni < 4; ++ni) {
                int n = wn * 64 + ni * 16 + t_l;
                bf[ni] = *(const f16x8*)(b_s + n * 64 + ((kb ^ (n & 7)) * 8));
            }
#pragma unroll
            for (int mi = 0; mi < 6; ++mi)
#pragma unroll
                for (int ni = 0; ni < 4; ++ni)
                    acc[mi][ni] = __builtin_amdgcn_mfma_f32_16x16x32_f16(af[mi], bf[ni], acc[mi][ni], 0, 0, 0);
        }
    }
    __syncthreads();
    // epilogue: acc + bias -> qkvT[n][m] f16, swizzled chunks
#pragma unroll
    for (int mi = 0; mi < 6; ++mi)
#pragma unroll
        for (int ni = 0; ni < 4; ++ni) {
            int n  = wn * 64 + ni * 16 + t_l;
            int mb = wm * 96 + mi * 16 + g * 4;
            int byte_off = n * 512 + (((mb >> 6) * 8 + (((mb >> 3) & 7) ^ (n & 7))) * 16) + (mb & 7) * 2;
            f16x4 hv;
#pragma unroll
            for (int r = 0; r < 4; ++r) hv[r] = (f16)(acc[mi][ni][r] + bias_s[mb + r]);
            *(f16x4*)(smem + byte_off) = hv;
        }
    __syncthreads();

    // ---- attention: wave w handles xx = 2w, 2w+1; all reads wave-private ----
#pragma unroll
    for (int xc = 0; xc < 2; ++xc) {
        const int xx = w * 2 + xc;
        const int nb = xx * 16;
        const int nrow = nb + t_l;           // own row (u for A-frag, t for B-frag)
        const int rbase = nrow * 512;
        const int sw = nrow & 7;

        // QK^T: S'[u][t] = sum_c K[c,u] Q[c,t]  (2 MFMAs over c)
        f32x4 s_acc = {0.f, 0.f, 0.f, 0.f};
#pragma unroll
        for (int half = 0; half < 2; ++half) {
            int qiA = (g + 4 * half) & 7;    // K chunk (region 1), m = 64 + g*8 + 32h
            f16x8 afr = *(const f16x8*)(smem + rbase + ((8 + (qiA ^ sw)) * 16));
            f16x8 bfr = *(const f16x8*)(smem + rbase + ((qiA ^ sw) * 16));  // Q region 0
            s_acc = __builtin_amdgcn_mfma_f32_16x16x32_f16(afr, bfr, s_acc, 0, 0, 0);
        }
        // rel-bias + wave-parallel softmax over u (4 regs + xor16/32)
        float sv[4];
#pragma unroll
        for (int r = 0; r < 4; ++r)
            sv[r] = s_acc[r] + pos_emb[h * 32 + t_l - (g * 4 + r) + 15];
        float mx = fmaxf(fmaxf(sv[0], sv[1]), fmaxf(sv[2], sv[3]));
        mx = fmaxf(mx, __shfl_xor(mx, 16));
        mx = fmaxf(mx, __shfl_xor(mx, 32));
        float es[4], ssum = 0.f;
#pragma unroll
        for (int r = 0; r < 4; ++r) { es[r] = __expf(sv[r] - mx); ssum += es[r]; }
        ssum += __shfl_xor(ssum, 16);
        ssum += __shfl_xor(ssum, 32);
        const float inv = 1.0f / ssum;
        f16x4 pfrag;                         // B-frag of PV directly (k=u, n=t)
#pragma unroll
        for (int r = 0; r < 4; ++r) pfrag[r] = (f16)(es[r] * inv);

        // PV: O[c][t] = sum_u V[u,c] P[u,t] via 16x16x16 MFMA, A = V^T
        f32x4 o_acc[4];
#pragma unroll
        for (int cb = 0; cb < 4; ++cb) {
            int mV = 128 + cb * 16 + t_l;
            int qiV = (mV >> 3) & 7;
            f16x4 vfrag;
#pragma unroll
            for (int j = 0; j < 4; ++j) {
                int nV = nb + g * 4 + j;
                vfrag[j] = *(const f16*)(smem + nV * 512 + ((16 + (qiV ^ (nV & 7))) * 16) + (mV & 7) * 2);
            }
            f32x4 z = {0.f, 0.f, 0.f, 0.f};
            o_acc[cb] = __builtin_amdgcn_mfma_f32_16x16x16f16(vfrag, pfrag, z, 0, 0, 0);
        }
        // write O[c][t] into dead Q/K chunks (q=0..15) of own row
#pragma unroll
        for (int cb = 0; cb < 4; ++cb) {
            int q = cb * 4 + g;
            int byte_off = rbase + (((q >> 3) * 8 + ((q & 7) ^ sw)) * 16);
            *(f32x4*)(smem + byte_off) = o_acc[cb];
        }
    }
    __syncthreads();

    // ---- final coalesced store: out[b][h*64+c][t][x0..x0+7] ----
    const int c = tid & 63, tq = tid >> 6;
    const int q = c >> 2;
#pragma unroll
    for (int ti = 0; ti < 4; ++ti) {
        int t = tq * 4 + ti;
        float vals[8];
#pragma unroll
        for (int xx = 0; xx < 8; ++xx) {
            int n2 = xx * 16 + t;
            vals[xx] = *(const float*)(smem + n2 * 512 + (((q >> 3) * 8 + ((q & 7) ^ (n2 & 7))) * 16) + (c & 3) * 4);
        }
        float4 lo = {vals[0], vals[1], vals[2], vals[3]};
        float4 hi = {vals[4], vals[5], vals[6], vals[7]};
        size_t oaddr = (((size_t)b * 512 + h * 64 + c) * 16 + t) * 2048 + x0;
        *(float4*)(out + oaddr) = lo;
        *(float4*)(out + oaddr + 4) = hi;
    }
}

// ---- k4_mfma: proj GEMM in-place on d_out, fp16 MFMA ----
__global__ __launch_bounds__(256) void k4_mfma(const f16* __restrict__ p16,
                                               const float* __restrict__ pb,
                                               float* __restrict__ io) {
    const int x0 = blockIdx.x * 64;
    const int t  = blockIdx.y;
    const int b  = blockIdx.z;
    const int tid = threadIdx.x, lane = tid & 63, w = tid >> 6;

    __shared__ __attribute__((aligned(16))) char smem4[81920];
    f16* in_sT = (f16*)smem4;             // [64 xx][512 c] swizzled
    f16* bp_s  = (f16*)(smem4 + 65536);   // [128 o][64 c] swizzled

    const size_t base_in = (((size_t)b * 512) * 16 + t) * 2048 + x0;
#pragma unroll
    for (int it = 0; it < 32; ++it) {
        int s = it * 256 + tid;            // 0..8191
        int c = s >> 4, xq = s & 15;
        float4 v = *(const float4*)(io + base_in + (size_t)c * 16 * 2048 + xq * 4);
        int kc = c >> 3, j = c & 7;
        float vv[4] = {v.x, v.y, v.z, v.w};
#pragma unroll
        for (int e = 0; e < 4; ++e) {
            int xx = xq * 4 + e;
            in_sT[xx * 512 + ((kc ^ (xx & 7)) * 8) + j] = (f16)vv[e];
        }
    }

    for (int no = 0; no < 4; ++no) {
        const int o_base = no * 128;
        f32x4 acc[4][2];
#pragma unroll
        for (int mi = 0; mi < 4; ++mi)
#pragma unroll
            for (int nj = 0; nj < 2; ++nj) acc[mi][nj] = (f32x4){0.f, 0.f, 0.f, 0.f};

        for (int ko = 0; ko < 8; ++ko) {
            __syncthreads();
#pragma unroll
            for (int it = 0; it < 4; ++it) {
                int s = it * 256 + tid;    // 0..1023
                int orow = s >> 3, ch = s & 7;
                uint4 v = *(const uint4*)(p16 + (size_t)(o_base + orow) * 512 + ko * 64 + ch * 8);
                *(uint4*)(bp_s + orow * 64 + ((ch ^ (orow & 7)) * 8)) = v;
            }
            __syncthreads();
#pragma unroll
            for (int kk = 0; kk < 2; ++kk) {
                const int kb4 = kk * 4 + (lane >> 4);
                f16x8 af[4], bf[2];
#pragma unroll
                for (int mi = 0; mi < 4; ++mi) {
                    int xx = mi * 16 + (lane & 15);
                    int kc = ko * 8 + kb4;
                    af[mi] = *(const f16x8*)(in_sT + xx * 512 + ((kc ^ (xx & 7)) * 8));
                }
#pragma unroll
                for (int nj = 0; nj < 2; ++nj) {
                    int orow = w * 32 + nj * 16 + (lane & 15);
                    bf[nj] = *(const f16x8*)(bp_s + orow * 64 + ((kb4 ^ (orow & 7)) * 8));
                }
#pragma unroll
                for (int mi = 0; mi < 4; ++mi)
#pragma unroll
                    for (int nj = 0; nj < 2; ++nj)
                        acc[mi][nj] = __builtin_amdgcn_mfma_f32_16x16x32_f16(af[mi], bf[nj], acc[mi][nj], 0, 0, 0);
            }
        }
#pragma unroll
        for (int mi = 0; mi < 4; ++mi)
#pragma unroll
            for (int nj = 0; nj < 2; ++nj) {
                int o = o_base + w * 32 + nj * 16 + (lane & 15);
                int xxb = mi * 16 + (lane >> 4) * 4;
                float bias = pb[o];
                float4 ov = {acc[mi][nj][0] + bias, acc[mi][nj][1] + bias,
                             acc[mi][nj][2] + bias, acc[mi][nj][3] + bias};
                *(float4*)(io + (((size_t)b * 512 + o) * 16 + t) * 2048 + x0 + xxb) = ov;
            }
    }
}

// ================= FALLBACK PATH (R1 fp32, proven) =================

__global__ __launch_bounds__(256) void k_qkv_attn(const float* __restrict__ x,
                                                  const float* __restrict__ qkv_w,
                                                  const float* __restrict__ sc,
                                                  const float* __restrict__ qbias,
                                                  const float* __restrict__ pos_emb,
                                                  float* __restrict__ out) {
    const int h  = blockIdx.x;
    const int x0 = blockIdx.y * 4;
    const int b  = blockIdx.z;
    const int tid = threadIdx.x;

    __shared__ float a_s[192][68];
    __shared__ float b_s[64][68];
    __shared__ float w_s[4][16][17];

    const int ty = tid >> 3;
    const int tx = tid & 7;

    float acc[6][8];
#pragma unroll
    for (int j = 0; j < 6; ++j)
#pragma unroll
        for (int k = 0; k < 8; ++k) acc[j][k] = 0.f;

    for (int ko = 0; ko < 512; ko += 64) {
        __syncthreads();
#pragma unroll
        for (int it = 0; it < 12; ++it) {
            int idx = it * 256 + tid;
            int m = idx >> 4;
            int c4 = (idx & 15) * 4;
            int g = m >> 6, i = m & 63;
            int o = g * 512 + h * 64 + i;
            float4 w4 = *(const float4*)(qkv_w + (size_t)o * 512 + ko + c4);
            float4 s4 = *(const float4*)(sc + b * 512 + ko + c4);
            float ksc = (g == 1) ? 0.125f : 1.0f;
            float4 v;
            v.x = w4.x * s4.x * ksc; v.y = w4.y * s4.y * ksc;
            v.z = w4.z * s4.z * ksc; v.w = w4.w * s4.w * ksc;
            *(float4*)&a_s[m][c4] = v;
        }
#pragma unroll
        for (int it = 0; it < 4; ++it) {
            int idx = it * 256 + tid;
            int cc = idx >> 4, t = idx & 15;
            float4 v = *(const float4*)(x + ((size_t)((b * 512 + ko + cc) * 16 + t)) * 2048 + x0);
            *(float4*)&b_s[cc][t * 4] = v;
        }
        __syncthreads();
#pragma unroll 4
        for (int cc = 0; cc < 64; ++cc) {
            float av[6];
#pragma unroll
            for (int j = 0; j < 6; ++j) av[j] = a_s[ty * 6 + j][cc];
            float4 b0 = *(const float4*)&b_s[cc][tx * 8];
            float4 b1 = *(const float4*)&b_s[cc][tx * 8 + 4];
            float bv[8] = {b0.x, b0.y, b0.z, b0.w, b1.x, b1.y, b1.z, b1.w};
#pragma unroll
            for (int j = 0; j < 6; ++j)
#pragma unroll
                for (int k = 0; k < 8; ++k)
                    acc[j][k] = fmaf(av[j], bv[k], acc[j][k]);
        }
    }
#pragma unroll
    for (int j = 0; j < 6; ++j) {
        int m = ty * 6 + j;
        int o = (m >> 6) * 512 + h * 64 + (m & 63);
        float qb = qbias[b * 1536 + o];
#pragma unroll
        for (int k = 0; k < 8; ++k) acc[j][k] += qb;
    }
    __syncthreads();
#pragma unroll
    for (int j = 0; j < 6; ++j)
#pragma unroll
        for (int k = 0; k < 8; ++k)
            a_s[ty * 6 + j][tx * 8 + k] = acc[j][k];
    __syncthreads();

    {
        const int xx = tid >> 6;
        const int t  = (tid >> 2) & 15;
        const int uq = tid & 3;
        float l[4] = {0.f, 0.f, 0.f, 0.f};
        for (int i = 0; i < 64; ++i) {
            float qv = a_s[i][t * 4 + xx];
#pragma unroll
            for (int uu = 0; uu < 4; ++uu)
                l[uu] = fmaf(qv, a_s[64 + i][(uq * 4 + uu) * 4 + xx], l[uu]);
        }
#pragma unroll
        for (int uu = 0; uu < 4; ++uu) {
            int u = uq * 4 + uu;
            w_s[xx][t][u] = l[uu] + pos_emb[h * 32 + t - u + 15];
        }
    }
    __syncthreads();
    if (tid < 64) {
        const int xx = tid >> 4, t = tid & 15;
        float mx = -3.4e38f;
#pragma unroll
        for (int u = 0; u < 16; ++u) mx = fmaxf(mx, w_s[xx][t][u]);
        float ssum = 0.f;
#pragma unroll
        for (int u = 0; u < 16; ++u) {
            float e = __expf(w_s[xx][t][u] - mx);
            w_s[xx][t][u] = e;
            ssum += e;
        }
        float inv = 1.0f / ssum;
#pragma unroll
        for (int u = 0; u < 16; ++u) w_s[xx][t][u] *= inv;
    }
    __syncthreads();
    {
        const int i  = tid & 63;
        const int t4 = tid >> 6;
        float4 varr[16];
#pragma unroll
        for (int u = 0; u < 16; ++u) varr[u] = *(const float4*)&a_s[128 + i][u * 4];
#pragma unroll
        for (int tt = 0; tt < 4; ++tt) {
            int t = t4 * 4 + tt;
            float4 o4 = {0.f, 0.f, 0.f, 0.f};
#pragma unroll
            for (int u = 0; u < 16; ++u) {
                o4.x = fmaf(w_s[0][t][u], varr[u].x, o4.x);
                o4.y = fmaf(w_s[1][t][u], varr[u].y, o4.y);
                o4.z = fmaf(w_s[2][t][u], varr[u].z, o4.z);
                o4.w = fmaf(w_s[3][t][u], varr[u].w, o4.w);
            }
            *(float4*)(out + ((size_t)((b * 512 + h * 64 + i) * 16 + t)) * 2048 + x0) = o4;
        }
    }
}

__global__ __launch_bounds__(256) void k_proj(const float* __restrict__ pw,
                                              const float* __restrict__ pb,
                                              float* __restrict__ io) {
    const int n0 = blockIdx.x * 32;
    const int b  = blockIdx.y;
    const int tid = threadIdx.x;
    __shared__ float in_s[512][36];
    __shared__ float w_s[128][65];

    {
        const float* src = io + (size_t)b * 512 * 32768 + n0;
#pragma unroll
        for (int it = 0; it < 64; ++it) {
            int idx = it * 256 + tid;
            int r = idx >> 5, j = idx & 31;
            in_s[r][j] = src[(size_t)r * 32768 + j];
        }
    }
    __syncthreads();

    const int ty = tid >> 3;
    const int tx = tid & 7;

    for (int mo = 0; mo < 512; mo += 128) {
        float acc[4][4];
#pragma unroll
        for (int j = 0; j < 4; ++j)
#pragma unroll
            for (int k = 0; k < 4; ++k) acc[j][k] = 0.f;

        for (int ko = 0; ko < 512; ko += 64) {
#pragma unroll
            for (int it = 0; it < 32; ++it) {
                int idx = it * 256 + tid;
                int m = idx >> 6, cc = idx & 63;
                w_s[m][cc] = pw[(size_t)(mo + m) * 512 + ko + cc];
            }
            __syncthreads();
#pragma unroll 4
            for (int cc = 0; cc < 64; ++cc) {
                float4 bv = *(const float4*)&in_s[ko + cc][tx * 4];
                float a0 = w_s[ty * 4 + 0][cc];
                float a1 = w_s[ty * 4 + 1][cc];
                float a2 = w_s[ty * 4 + 2][cc];
                float a3 = w_s[ty * 4 + 3][cc];
                acc[0][0] = fmaf(a0, bv.x, acc[0][0]); acc[0][1] = fmaf(a0, bv.y, acc[0][1]);
                acc[0][2] = fmaf(a0, bv.z, acc[0][2]); acc[0][3] = fmaf(a0, bv.w, acc[0][3]);
                acc[1][0] = fmaf(a1, bv.x, acc[1][0]); acc[1][1] = fmaf(a1, bv.y, acc[1][1]);
                acc[1][2] = fmaf(a1, bv.z, acc[1][2]); acc[1][3] = fmaf(a1, bv.w, acc[1][3]);
                acc[2][0] = fmaf(a2, bv.x, acc[2][0]); acc[2][1] = fmaf(a2, bv.y, acc[2][1]);
                acc[2][2] = fmaf(a2, bv.z, acc[2][2]); acc[2][3] = fmaf(a2, bv.w, acc[2][3]);
                acc[3][0] = fmaf(a3, bv.x, acc[3][0]); acc[3][1] = fmaf(a3, bv.y, acc[3][1]);
                acc[3][2] = fmaf(a3, bv.z, acc[3][2]); acc[3][3] = fmaf(a3, bv.w, acc[3][3]);
            }
            __syncthreads();
        }
#pragma unroll
        for (int j = 0; j < 4; ++j) {
            int m = mo + ty * 4 + j;
            float bias = pb[m];
            float4 o4 = {acc[j][0] + bias, acc[j][1] + bias, acc[j][2] + bias, acc[j][3] + bias};
            *(float4*)(io + (size_t)(b * 512 + m) * 32768 + n0 + tx * 4) = o4;
        }
    }
}

extern "C" void kernel_launch(void* const* d_in, const int* in_sizes, int n_in,
                              void* d_out, int out_size, void* d_ws, size_t ws_size,
                              hipStream_t stream) {
    (void)in_sizes; (void)n_in; (void)out_size;
    const float* x       = (const float*)d_in[0];
    const float* gn_w    = (const float*)d_in[1];
    const float* gn_b    = (const float*)d_in[2];
    const float* qkv_w   = (const float*)d_in[3];
    const float* qkv_b   = (const float*)d_in[4];
    const float* proj_w  = (const float*)d_in[5];
    const float* proj_b  = (const float*)d_in[6];
    const float* pos_emb = (const float*)d_in[7];
    float* out = (float*)d_out;

    float* ws    = (float*)d_ws;
    float* psum  = ws;            // 2048
    float* psq   = ws + 2048;     // 2048
    float* mu    = ws + 4096;     // 128
    float* rs    = ws + 4224;     // 128
    float* sc    = ws + 4352;     // 2048
    float* beta  = ws + 6400;     // 2048
    float* qbias = ws + 8448;     // 6144

    const size_t W16_OFF = 65536;
    const size_t P16_OFF = W16_OFF + (size_t)1536 * 512 * 2;
    const size_t XT_OFF  = P16_OFF + (size_t)512 * 512 * 2;
    const size_t NEEDED  = XT_OFF + (size_t)4 * 2048 * 16 * 512 * 2;

    k_gn_part<<<dim3(2048), dim3(256), 0, stream>>>(x, psum, psq);
    k_gn_final<<<dim3(1), dim3(128), 0, stream>>>(psum, psq, mu, rs);
    k_fold_sc<<<dim3(8), dim3(256), 0, stream>>>(gn_w, gn_b, mu, rs, sc, beta);

    if (ws_size >= NEEDED) {
        f16* w16 = (f16*)((char*)d_ws + W16_OFF);
        f16* p16 = (f16*)((char*)d_ws + P16_OFF);
        f16* xT  = (f16*)((char*)d_ws + XT_OFF);
        k_prep_w<<<dim3(1024), dim3(256), 0, stream>>>(qkv_w, proj_w, w16, p16);
        k_xt<<<dim3(32, 8, 64), dim3(256), 0, stream>>>(x, sc, beta, xT);
        k3_mfma<<<dim3(8, 256, 4), dim3(256), 0, stream>>>(xT, w16, qkv_b, pos_emb, out);
        k4_mfma<<<dim3(32, 16, 4), dim3(256), 0, stream>>>(p16, proj_b, out);
    } else {
        k_fold_bias<<<dim3(24), dim3(256), 0, stream>>>(qkv_w, qkv_b, beta, qbias);
        k_qkv_attn<<<dim3(8, 512, 4), dim3(256), 0, stream>>>(x, qkv_w, sc, qbias, pos_emb, out);
        k_proj<<<dim3(1024, 4), dim3(256), 0, stream>>>(proj_w, proj_b, out);
    }
}